// Round 2
// baseline (1173.365 us; speedup 1.0000x reference)
//
#include <hip/hip_runtime.h>
#include <hip/hip_bf16.h>
#include <stdint.h>

#define B_   128
#define LT   256
#define LI   576
#define HD   1024
#define SMOOTHF 9.0f
#define EPSF 1e-8f

typedef __bf16 bf16x8 __attribute__((ext_vector_type(8)));
typedef float  f32x4  __attribute__((ext_vector_type(4)));

__device__ inline ushort f2b(float f) {
  uint32_t u = __float_as_uint(f);
  u += 0x7FFFu + ((u >> 16) & 1u);   // RNE
  return (ushort)(u >> 16);
}

// ---------------- fp32 -> bf16 conversion (vectorized) ----------------
__global__ __launch_bounds__(256) void cvt_bf16_kernel(
    const float* __restrict__ in, ushort* __restrict__ out, int n4) {
  int idx = blockIdx.x * blockDim.x + threadIdx.x;
  int stride = gridDim.x * blockDim.x;
  for (int i = idx; i < n4; i += stride) {
    float4 v = reinterpret_cast<const float4*>(in)[i];
    ushort4 o = make_ushort4(f2b(v.x), f2b(v.y), f2b(v.z), f2b(v.w));
    reinterpret_cast<ushort4*>(out)[i] = o;
  }
}

// ---------------- unified bf16 MFMA GEMM, 64x64 tile, 4 waves ----------------
// C[m,n] = sum_k A[m,k] * B'[k,n]
//   BT=false: B given as [N,K] row-major (NT; K contiguous)
//   BT=true : B given as [K,N] row-major (NN; staged transposed into LDS)
template<bool BT, bool OUT_BF16, bool RELU_BIAS>
__global__ __launch_bounds__(256)
void gemm64(const ushort* __restrict__ A, const ushort* __restrict__ Bm,
            const float* __restrict__ bias, void* __restrict__ C,
            int M, int N, int K,
            long sA, long sB, long sC, int lda, int ldb, int ldc)
{
  __shared__ ushort As[64][64];
  __shared__ ushort Bs[64][64];   // always [n][k] layout for fragment reads
  const int b = blockIdx.y;
  const int ntiles = N >> 6;
  const int m0 = (blockIdx.x / ntiles) << 6;
  const int n0 = (blockIdx.x % ntiles) << 6;
  const ushort* Ab = A + (size_t)b * sA;
  const ushort* Bb = Bm + (size_t)b * sB;

  const int t    = threadIdx.x;
  const int lane = t & 63, wid = t >> 6;
  const int wr = wid >> 1, wc = wid & 1;      // 2x2 wave grid, 32x32 per wave
  const int r16 = lane & 15, g = lane >> 4;   // fragment row / k-group

  const int arow = t >> 3;           // 0..31
  const int acol = (t & 7) << 3;     // 0..56, 8 bf16 chunks

  f32x4 acc[2][2] = {};

  for (int k0 = 0; k0 < K; k0 += 64) {
    { // stage A tile [64][64], row-major K-contiguous
      const ushort* src = Ab + (size_t)(m0 + arow) * lda + k0 + acol;
      uint4 v0 = *reinterpret_cast<const uint4*>(src);
      uint4 v1 = *reinterpret_cast<const uint4*>(src + (size_t)32 * lda);
      *reinterpret_cast<uint4*>(&As[arow][acol])      = v0;
      *reinterpret_cast<uint4*>(&As[arow + 32][acol]) = v1;
    }
    if (!BT) { // B rows are output cols, K contiguous
      const ushort* src = Bb + (size_t)(n0 + arow) * ldb + k0 + acol;
      uint4 v0 = *reinterpret_cast<const uint4*>(src);
      uint4 v1 = *reinterpret_cast<const uint4*>(src + (size_t)32 * ldb);
      *reinterpret_cast<uint4*>(&Bs[arow][acol])      = v0;
      *reinterpret_cast<uint4*>(&Bs[arow + 32][acol]) = v1;
    } else {   // B is [K][N]; transpose-stage into Bs[n][k]
      const int kp = t >> 3;          // k-pair 0..31
      const int nc = (t & 7) << 3;    // 0..56
      const ushort* src = Bb + (size_t)(k0 + 2 * kp) * ldb + n0 + nc;
      uint4 u0 = *reinterpret_cast<const uint4*>(src);
      uint4 u1 = *reinterpret_cast<const uint4*>(src + ldb);
      ushort e0[8], e1[8];
      *reinterpret_cast<uint4*>(e0) = u0;
      *reinterpret_cast<uint4*>(e1) = u1;
      uint32_t* B32 = reinterpret_cast<uint32_t*>(&Bs[0][0]);
      #pragma unroll
      for (int e = 0; e < 8; ++e)
        B32[(nc + e) * 32 + kp] = (uint32_t)e0[e] | ((uint32_t)e1[e] << 16);
    }
    __syncthreads();
    #pragma unroll
    for (int kk = 0; kk < 2; ++kk) {
      bf16x8 af[2], bfr[2];
      #pragma unroll
      for (int fr = 0; fr < 2; ++fr) {
        af[fr]  = *reinterpret_cast<const bf16x8*>(&As[wr * 32 + fr * 16 + r16][kk * 32 + g * 8]);
        bfr[fr] = *reinterpret_cast<const bf16x8*>(&Bs[wc * 32 + fr * 16 + r16][kk * 32 + g * 8]);
      }
      #pragma unroll
      for (int fr = 0; fr < 2; ++fr)
        #pragma unroll
        for (int fc = 0; fc < 2; ++fc)
          acc[fr][fc] = __builtin_amdgcn_mfma_f32_16x16x32_bf16(af[fr], bfr[fc], acc[fr][fc], 0, 0, 0);
    }
    __syncthreads();
  }

  // epilogue: C/D layout col=lane&15, row=(lane>>4)*4+reg  [m89-verified]
  #pragma unroll
  for (int fr = 0; fr < 2; ++fr) {
    #pragma unroll
    for (int fc = 0; fc < 2; ++fc) {
      #pragma unroll
      for (int r = 0; r < 4; ++r) {
        int row = m0 + wr * 32 + fr * 16 + g * 4 + r;
        int col = n0 + wc * 32 + fc * 16 + r16;
        float v = acc[fr][fc][r];
        if (RELU_BIAS) v = fmaxf(v + bias[col], 0.0f);
        size_t off = (size_t)b * sC + (size_t)row * ldc + col;
        if (OUT_BF16) reinterpret_cast<ushort*>(C)[off] = f2b(v);
        else          reinterpret_cast<float*>(C)[off]  = v;
      }
    }
  }
}

// ---------------- relu row sums: rs_t[b,i] = sum_t relu(G[b,i,t]) ----------------
__global__ __launch_bounds__(256) void rowsum_relu_kernel(
    const float* __restrict__ G, float* __restrict__ rs) {
  int row  = blockIdx.x * 4 + (threadIdx.x >> 6);  // (b,i) flat
  int lane = threadIdx.x & 63;
  float4 v = reinterpret_cast<const float4*>(G + (size_t)row * LT)[lane];
  float s = fmaxf(v.x, 0.f) + fmaxf(v.y, 0.f) + fmaxf(v.z, 0.f) + fmaxf(v.w, 0.f);
  #pragma unroll
  for (int off = 32; off > 0; off >>= 1) s += __shfl_xor(s, off);
  if (lane == 0) rs[row] = s;
}

// ---------------- relu col sums: rs_i[b,t] = sum_i relu(G[b,i,t]) ----------------
__global__ __launch_bounds__(256) void colsum_relu_kernel(
    const float* __restrict__ G, float* __restrict__ rs) {
  int b = blockIdx.x, t = threadIdx.x;
  const float* g = G + (size_t)b * LI * LT + t;
  float s = 0.f;
  for (int i = 0; i < LI; ++i) s += fmaxf(g[(size_t)i * LT], 0.f);
  rs[b * LT + t] = s;
}

// ---------------- attn_txt[b,i,t] = softmax_t( 9*relu(G[b,i,t]) / (rs_i[b,t]+eps) ) ----------------
__global__ __launch_bounds__(256) void attn_txt_kernel(
    const float* __restrict__ G, const float* __restrict__ rs_i,
    float* __restrict__ out_f32, ushort* __restrict__ out_bf16) {
  int row  = blockIdx.x * 4 + (threadIdx.x >> 6);  // (b,i) flat
  int b    = row / LI;
  int lane = threadIdx.x & 63;
  float4 gv = reinterpret_cast<const float4*>(G + (size_t)row * LT)[lane];
  float4 dv = reinterpret_cast<const float4*>(rs_i + (size_t)b * LT)[lane];
  float x0 = SMOOTHF * fmaxf(gv.x, 0.f) / (dv.x + EPSF);
  float x1 = SMOOTHF * fmaxf(gv.y, 0.f) / (dv.y + EPSF);
  float x2 = SMOOTHF * fmaxf(gv.z, 0.f) / (dv.z + EPSF);
  float x3 = SMOOTHF * fmaxf(gv.w, 0.f) / (dv.w + EPSF);
  float m = fmaxf(fmaxf(x0, x1), fmaxf(x2, x3));
  #pragma unroll
  for (int off = 32; off > 0; off >>= 1) m = fmaxf(m, __shfl_xor(m, off));
  float e0 = __expf(x0 - m), e1 = __expf(x1 - m), e2 = __expf(x2 - m), e3 = __expf(x3 - m);
  float s = e0 + e1 + e2 + e3;
  #pragma unroll
  for (int off = 32; off > 0; off >>= 1) s += __shfl_xor(s, off);
  float inv = 1.0f / s;
  float4 o = make_float4(e0 * inv, e1 * inv, e2 * inv, e3 * inv);
  reinterpret_cast<float4*>(out_f32 + (size_t)row * LT)[lane] = o;
  ushort4 ob = make_ushort4(f2b(o.x), f2b(o.y), f2b(o.z), f2b(o.w));
  reinterpret_cast<ushort4*>(out_bf16 + (size_t)row * LT)[lane] = ob;
}

// ---------------- attn_img softmax stats over i (split into 4 i-chunks) ----------------
__global__ __launch_bounds__(256) void attn_img_stats_kernel(
    const float* __restrict__ G, const float* __restrict__ rs_t,
    float* __restrict__ pm, float* __restrict__ ps) {
  __shared__ float inv_l[LI / 4];
  int b = blockIdx.x, iq = blockIdx.y, t = threadIdx.x;
  int i0 = iq * (LI / 4);
  for (int i = t; i < LI / 4; i += 256)
    inv_l[i] = SMOOTHF / (rs_t[b * LI + i0 + i] + EPSF);
  __syncthreads();
  const float* g = G + (size_t)b * LI * LT + (size_t)i0 * LT + t;
  float m = -1e30f, s = 0.f;
  for (int i = 0; i < LI / 4; ++i) {
    float x  = fmaxf(g[(size_t)i * LT], 0.f) * inv_l[i];
    float mn = fmaxf(m, x);
    s = s * __expf(m - mn) + __expf(x - mn);
    m = mn;
  }
  pm[(b * 4 + iq) * LT + t] = m;
  ps[(b * 4 + iq) * LT + t] = s;
}

__global__ __launch_bounds__(256) void attn_img_combine_kernel(
    const float* __restrict__ pm, const float* __restrict__ ps,
    float* __restrict__ m_out, float* __restrict__ s_out) {
  int b = blockIdx.x, t = threadIdx.x;
  float m = -1e30f;
  #pragma unroll
  for (int q = 0; q < 4; ++q) m = fmaxf(m, pm[(b * 4 + q) * LT + t]);
  float s = 0.f;
  #pragma unroll
  for (int q = 0; q < 4; ++q) s += ps[(b * 4 + q) * LT + t] * __expf(pm[(b * 4 + q) * LT + t] - m);
  m_out[b * LT + t] = m;
  s_out[b * LT + t] = s;
}

// ---------------- attn_img writer (transpose G[i,t] -> attn[t,i] via LDS tile) ----------------
__global__ __launch_bounds__(256) void attn_img_write_kernel(
    const float* __restrict__ G, const float* __restrict__ rs_t,
    const float* __restrict__ m_in, const float* __restrict__ s_in,
    float* __restrict__ out_f32, ushort* __restrict__ out_bf16) {
  __shared__ float T[64][65];
  int b  = blockIdx.y;
  int ti = blockIdx.x % (LI / 64);  // i tile (9)
  int tt = blockIdx.x / (LI / 64);  // t tile (4)
  int i0 = ti * 64, t0 = tt * 64;
  int tid = threadIdx.x;
  #pragma unroll
  for (int j = 0; j < 4; ++j) {
    int q = tid + j * 256;           // 1024 float4 chunks
    int row = q >> 4;                // i within tile
    int c4  = (q & 15) << 2;         // t within tile
    float4 gv = *reinterpret_cast<const float4*>(G + (size_t)b * LI * LT + (size_t)(i0 + row) * LT + t0 + c4);
    float inv = SMOOTHF / (rs_t[b * LI + i0 + row] + EPSF);
    float4 mt = *reinterpret_cast<const float4*>(m_in + b * LT + t0 + c4);
    float4 st = *reinterpret_cast<const float4*>(s_in + b * LT + t0 + c4);
    T[c4 + 0][row] = __expf(fmaxf(gv.x, 0.f) * inv - mt.x) / st.x;
    T[c4 + 1][row] = __expf(fmaxf(gv.y, 0.f) * inv - mt.y) / st.y;
    T[c4 + 2][row] = __expf(fmaxf(gv.z, 0.f) * inv - mt.z) / st.z;
    T[c4 + 3][row] = __expf(fmaxf(gv.w, 0.f) * inv - mt.w) / st.w;
  }
  __syncthreads();
  #pragma unroll
  for (int j = 0; j < 4; ++j) {
    int q = tid + j * 256;
    int row = q >> 4;                // t within tile
    int c4  = (q & 15) << 2;         // i within tile
    float4 o = make_float4(T[row][c4], T[row][c4 + 1], T[row][c4 + 2], T[row][c4 + 3]);
    size_t off = (size_t)b * LT * LI + (size_t)(t0 + row) * LI + i0 + c4;
    *reinterpret_cast<float4*>(out_f32 + off) = o;
    ushort4 ob = make_ushort4(f2b(o.x), f2b(o.y), f2b(o.z), f2b(o.w));
    *reinterpret_cast<ushort4*>(out_bf16 + off) = ob;
  }
}

// ---------------- launch ----------------
extern "C" void kernel_launch(void* const* d_in, const int* in_sizes, int n_in,
                              void* d_out, int out_size, void* d_ws, size_t ws_size,
                              hipStream_t stream) {
  const float* txt   = (const float*)d_in[0];
  const float* img   = (const float*)d_in[1];
  const float* W_txt = (const float*)d_in[2];
  const float* b_txt = (const float*)d_in[3];
  const float* W_img = (const float*)d_in[4];
  const float* b_img = (const float*)d_in[5];

  float* out          = (float*)d_out;
  float* out_txt      = out;                                  // [128,256,1024]
  float* out_img      = out + (size_t)B_ * LT * HD;           // [128,576,1024]
  float* out_attn_img = out_img + (size_t)B_ * LI * HD;       // [128,256,576]
  float* out_attn_txt = out_attn_img + (size_t)B_ * LT * LI;  // [128,576,256]

  char* w = (char*)d_ws;
  auto alloc = [&](size_t bytes) -> char* {
    char* p = w; w += (bytes + 255) & ~(size_t)255; return p;
  };
  ushort* txt_b  = (ushort*)alloc((size_t)B_ * LT * HD * 2);
  ushort* img_b  = (ushort*)alloc((size_t)B_ * LI * HD * 2);
  ushort* Wt_b   = (ushort*)alloc((size_t)HD * HD * 2);
  ushort* Wi_b   = (ushort*)alloc((size_t)HD * HD * 2);
  float*  Gm     = (float*) alloc((size_t)B_ * LI * LT * 4);
  float*  rs_t   = (float*) alloc((size_t)B_ * LI * 4);
  float*  rs_i   = (float*) alloc((size_t)B_ * LT * 4);
  float*  pm     = (float*) alloc((size_t)B_ * 4 * LT * 4);
  float*  ps     = (float*) alloc((size_t)B_ * 4 * LT * 4);
  float*  mi     = (float*) alloc((size_t)B_ * LT * 4);
  float*  si     = (float*) alloc((size_t)B_ * LT * 4);
  ushort* ai_b   = (ushort*)alloc((size_t)B_ * LT * LI * 2);  // attn_img bf16
  ushort* at_b   = (ushort*)alloc((size_t)B_ * LI * LT * 2);  // attn_txt bf16
  ushort* txtAE  = (ushort*)alloc((size_t)B_ * LT * HD * 2);
  ushort* imgAE  = (ushort*)alloc((size_t)B_ * LI * HD * 2);
  (void)ws_size; (void)in_sizes; (void)n_in; (void)out_size;  // ~571 MB required

  // bf16 conversions
  cvt_bf16_kernel<<<2048, 256, 0, stream>>>(txt, txt_b, B_ * LT * HD / 4);
  cvt_bf16_kernel<<<2048, 256, 0, stream>>>(img, img_b, B_ * LI * HD / 4);
  cvt_bf16_kernel<<<1024, 256, 0, stream>>>(W_txt, Wt_b, HD * HD / 4);
  cvt_bf16_kernel<<<1024, 256, 0, stream>>>(W_img, Wi_b, HD * HD / 4);

  // G[b,i,t] = img[b,i,:] . txt[b,t,:]
  dim3 gG((LI / 64) * (LT / 64), B_);
  gemm64<false, false, false><<<gG, 256, 0, stream>>>(
      img_b, txt_b, nullptr, Gm, LI, LT, HD,
      (long)LI * HD, (long)LT * HD, (long)LI * LT, HD, HD, LT);

  rowsum_relu_kernel<<<B_ * LI / 4, 256, 0, stream>>>(Gm, rs_t);
  colsum_relu_kernel<<<B_, 256, 0, stream>>>(Gm, rs_i);

  attn_txt_kernel<<<B_ * LI / 4, 256, 0, stream>>>(Gm, rs_i, out_attn_txt, at_b);

  attn_img_stats_kernel<<<dim3(B_, 4), 256, 0, stream>>>(Gm, rs_t, pm, ps);
  attn_img_combine_kernel<<<B_, 256, 0, stream>>>(pm, ps, mi, si);
  attn_img_write_kernel<<<dim3((LT / 64) * (LI / 64), B_), 256, 0, stream>>>(
      Gm, rs_t, mi, si, out_attn_img, ai_b);

  // txtAE = attn_img . img   (B K-major -> BT staging)
  dim3 g1((LT / 64) * (HD / 64), B_);
  gemm64<true, true, false><<<g1, 256, 0, stream>>>(
      ai_b, img_b, nullptr, txtAE, LT, HD, LI,
      (long)LT * LI, (long)LI * HD, (long)LT * HD, LI, HD, HD);

  // imgAE = attn_txt . txt
  dim3 g2((LI / 64) * (HD / 64), B_);
  gemm64<true, true, false><<<g2, 256, 0, stream>>>(
      at_b, txt_b, nullptr, imgAE, LI, HD, LT,
      (long)LI * LT, (long)LT * HD, (long)LI * HD, LT, HD, HD);

  // FC heads: relu(x @ W^T + b)  (W is [o,h] row-major -> NT directly)
  gemm64<false, false, true><<<g1, 256, 0, stream>>>(
      txtAE, Wt_b, b_txt, out_txt, LT, HD, HD,
      (long)LT * HD, 0L, (long)LT * HD, HD, HD, HD);
  gemm64<false, false, true><<<g2, 256, 0, stream>>>(
      imgAE, Wi_b, b_img, out_img, LI, HD, HD,
      (long)LI * HD, 0L, (long)LI * HD, HD, HD, HD);
}

// Round 3
// 941.622 us; speedup vs baseline: 1.2461x; 1.2461x over previous
//
#include <hip/hip_runtime.h>
#include <hip/hip_bf16.h>
#include <stdint.h>

#define B_   128
#define LT   256
#define LI   576
#define HD   1024
#define SMOOTHF 9.0f
#define EPSF 1e-8f

typedef __bf16 bf16x8 __attribute__((ext_vector_type(8)));
typedef float  f32x4  __attribute__((ext_vector_type(4)));

__device__ inline ushort f2b(float f) {
  uint32_t u = __float_as_uint(f);
  u += 0x7FFFu + ((u >> 16) & 1u);   // RNE
  return (ushort)(u >> 16);
}

// async global->LDS, 16B per lane. LDS dest must be wave-uniform base (lane*16 auto).
__device__ __forceinline__ void gload_lds16(const ushort* g, ushort* l) {
  __builtin_amdgcn_global_load_lds(
      (const __attribute__((address_space(1))) unsigned int*)(g),
      (__attribute__((address_space(3))) unsigned int*)(l),
      16, 0, 0);
}

// ---------------- fp32 -> bf16 conversion (vectorized) ----------------
__global__ __launch_bounds__(256) void cvt_bf16_kernel(
    const float* __restrict__ in, ushort* __restrict__ out, int n4) {
  int idx = blockIdx.x * blockDim.x + threadIdx.x;
  int stride = gridDim.x * blockDim.x;
  for (int i = idx; i < n4; i += stride) {
    float4 v = reinterpret_cast<const float4*>(in)[i];
    ushort4 o = make_ushort4(f2b(v.x), f2b(v.y), f2b(v.z), f2b(v.w));
    reinterpret_cast<ushort4*>(out)[i] = o;
  }
}

// ---------------- m97-structure GEMM: 128x128 tile, BK=64, 4 waves ----------------
// C[m,n] = sum_k A[m,k]*B'[k,n].  A always [M,K] row-major (K contig).
//  BT=false: B given [N,K] row-major -> global_load_lds staging.
//  BT=true : B given [K,N] row-major -> LDS transpose staging (padded rows).
//  MPRED: M not multiple of 128 -> clamp loads, predicate stores.
template<bool BT, bool MPRED, bool OUT_BF16, bool RELU_BIAS, bool SWZ>
__global__ __launch_bounds__(256)
void gemm128(const ushort* __restrict__ A, const ushort* __restrict__ Bm,
             const float* __restrict__ bias, void* __restrict__ C,
             int M, int N, int K,
             long sA, long sB, long sC, int lda, int ldb, int ldc)
{
  __shared__ ushort As[128][64];
  __shared__ ushort Bs[128][BT ? 72 : 64];   // pad BT rows: 144B stride spreads banks
  const int b = blockIdx.y;
  int bid = blockIdx.x;
  if (SWZ) {                                  // XCD-aware swizzle (nwg % 8 == 0)
    int cpx = gridDim.x >> 3;
    bid = (bid & 7) * cpx + (bid >> 3);
  }
  const int ntiles = N >> 7;
  const int m0 = (bid / ntiles) << 7;
  const int n0 = (bid % ntiles) << 7;
  const ushort* Ab = A + (size_t)b * sA;
  const ushort* Bb = Bm + (size_t)b * sB;

  const int t    = threadIdx.x;
  const int lane = t & 63, w = t >> 6;
  const int wr = w >> 1, wc = w & 1;          // 2x2 waves, 64x64 out each
  const int r16 = lane & 15, g = lane >> 4;   // frag row / k-group

  const int srow = lane >> 3;                 // 0..7  (staging row within wave chunk)
  const int scol = (lane & 7) << 3;           // 0..56 (staging col, 8 bf16 = 16B)

  f32x4 acc[4][4] = {};

  for (int k0 = 0; k0 < K; k0 += 64) {
    // ---- stage A tile [128][64] via async 16B loads (linear LDS) ----
    #pragma unroll
    for (int j = 0; j < 4; ++j) {
      int row = j * 32 + w * 8 + srow;
      int ar = m0 + row;
      if (MPRED) ar = ar < M ? ar : M - 1;
      gload_lds16(Ab + (size_t)ar * lda + k0 + scol, &As[0][0] + j * 2048 + w * 512);
    }
    if (!BT) {
      #pragma unroll
      for (int j = 0; j < 4; ++j) {
        int row = j * 32 + w * 8 + srow;
        gload_lds16(Bb + (size_t)(n0 + row) * ldb + k0 + scol, &Bs[0][0] + j * 2048 + w * 512);
      }
    } else {
      // transpose-stage: B[K][N] rows -> Bs[n][k] (rows padded to 72)
      const int kp = t >> 3;            // k-pair 0..31
      const int nc = (t & 7) << 3;      // 0..56
      uint32_t* B32 = reinterpret_cast<uint32_t*>(&Bs[0][0]);
      #pragma unroll
      for (int h = 0; h < 2; ++h) {
        const ushort* srcB = Bb + (size_t)(k0 + 2 * kp) * ldb + n0 + nc + h * 64;
        uint4 u0 = *reinterpret_cast<const uint4*>(srcB);
        uint4 u1 = *reinterpret_cast<const uint4*>(srcB + ldb);
        ushort e0[8], e1[8];
        *reinterpret_cast<uint4*>(e0) = u0;
        *reinterpret_cast<uint4*>(e1) = u1;
        #pragma unroll
        for (int e = 0; e < 8; ++e)
          B32[(size_t)(nc + h * 64 + e) * 36 + kp] = (uint32_t)e0[e] | ((uint32_t)e1[e] << 16);
      }
    }
    __syncthreads();
    // ---- 32 MFMA per wave per K-step ----
    #pragma unroll
    for (int kk = 0; kk < 2; ++kk) {
      bf16x8 af[4], bf[4];
      #pragma unroll
      for (int f = 0; f < 4; ++f) {
        af[f] = *reinterpret_cast<const bf16x8*>(&As[wr * 64 + f * 16 + r16][kk * 32 + g * 8]);
        bf[f] = *reinterpret_cast<const bf16x8*>(&Bs[wc * 64 + f * 16 + r16][kk * 32 + g * 8]);
      }
      #pragma unroll
      for (int fr = 0; fr < 4; ++fr)
        #pragma unroll
        for (int fc = 0; fc < 4; ++fc)
          acc[fr][fc] = __builtin_amdgcn_mfma_f32_16x16x32_bf16(af[fr], bf[fc], acc[fr][fc], 0, 0, 0);
    }
    __syncthreads();
  }

  // ---- epilogue: C/D layout col=lane&15, row=(lane>>4)*4+reg [m89-verified] ----
  #pragma unroll
  for (int fr = 0; fr < 4; ++fr) {
    int rbase = m0 + wr * 64 + fr * 16 + g * 4;
    #pragma unroll
    for (int r = 0; r < 4; ++r) {
      if (MPRED && (rbase + r >= M)) continue;
      size_t off0 = (size_t)b * sC + (size_t)(rbase + r) * ldc + n0 + wc * 64;
      #pragma unroll
      for (int fc = 0; fc < 4; ++fc) {
        int col = fc * 16 + r16;
        float v = acc[fr][fc][r];
        if (RELU_BIAS) v = fmaxf(v + bias[n0 + wc * 64 + col], 0.0f);
        if (OUT_BF16) reinterpret_cast<ushort*>(C)[off0 + col] = f2b(v);
        else          reinterpret_cast<float*>(C)[off0 + col]  = v;
      }
    }
  }
}

// ---------------- relu row sums: rs_t[b,i] = sum_t relu(G[b,i,t]) ----------------
__global__ __launch_bounds__(256) void rowsum_relu_kernel(
    const float* __restrict__ G, float* __restrict__ rs) {
  int row  = blockIdx.x * 4 + (threadIdx.x >> 6);
  int lane = threadIdx.x & 63;
  float4 v = reinterpret_cast<const float4*>(G + (size_t)row * LT)[lane];
  float s = fmaxf(v.x, 0.f) + fmaxf(v.y, 0.f) + fmaxf(v.z, 0.f) + fmaxf(v.w, 0.f);
  #pragma unroll
  for (int off = 32; off > 0; off >>= 1) s += __shfl_xor(s, off);
  if (lane == 0) rs[row] = s;
}

// ---------------- relu col sums: rs_i[b,t] = sum_i relu(G[b,i,t]) ----------------
__global__ __launch_bounds__(256) void colsum_relu_kernel(
    const float* __restrict__ G, float* __restrict__ rs) {
  int b = blockIdx.x, t = threadIdx.x;
  const float* g = G + (size_t)b * LI * LT + t;
  float s = 0.f;
  for (int i = 0; i < LI; ++i) s += fmaxf(g[(size_t)i * LT], 0.f);
  rs[b * LT + t] = s;
}

// ---------------- attn_txt[b,i,t] = softmax_t( 9*relu(G)/rs_i ) ----------------
__global__ __launch_bounds__(256) void attn_txt_kernel(
    const float* __restrict__ G, const float* __restrict__ rs_i,
    float* __restrict__ out_f32, ushort* __restrict__ out_bf16) {
  int row  = blockIdx.x * 4 + (threadIdx.x >> 6);
  int b    = row / LI;
  int lane = threadIdx.x & 63;
  float4 gv = reinterpret_cast<const float4*>(G + (size_t)row * LT)[lane];
  float4 dv = reinterpret_cast<const float4*>(rs_i + (size_t)b * LT)[lane];
  float x0 = SMOOTHF * fmaxf(gv.x, 0.f) / (dv.x + EPSF);
  float x1 = SMOOTHF * fmaxf(gv.y, 0.f) / (dv.y + EPSF);
  float x2 = SMOOTHF * fmaxf(gv.z, 0.f) / (dv.z + EPSF);
  float x3 = SMOOTHF * fmaxf(gv.w, 0.f) / (dv.w + EPSF);
  float m = fmaxf(fmaxf(x0, x1), fmaxf(x2, x3));
  #pragma unroll
  for (int off = 32; off > 0; off >>= 1) m = fmaxf(m, __shfl_xor(m, off));
  float e0 = __expf(x0 - m), e1 = __expf(x1 - m), e2 = __expf(x2 - m), e3 = __expf(x3 - m);
  float s = e0 + e1 + e2 + e3;
  #pragma unroll
  for (int off = 32; off > 0; off >>= 1) s += __shfl_xor(s, off);
  float inv = 1.0f / s;
  float4 o = make_float4(e0 * inv, e1 * inv, e2 * inv, e3 * inv);
  reinterpret_cast<float4*>(out_f32 + (size_t)row * LT)[lane] = o;
  ushort4 ob = make_ushort4(f2b(o.x), f2b(o.y), f2b(o.z), f2b(o.w));
  reinterpret_cast<ushort4*>(out_bf16 + (size_t)row * LT)[lane] = ob;
}

// ---------------- attn_img softmax stats over i (4 i-chunks) ----------------
__global__ __launch_bounds__(256) void attn_img_stats_kernel(
    const float* __restrict__ G, const float* __restrict__ rs_t,
    float* __restrict__ pm, float* __restrict__ ps) {
  __shared__ float inv_l[LI / 4];
  int b = blockIdx.x, iq = blockIdx.y, t = threadIdx.x;
  int i0 = iq * (LI / 4);
  for (int i = t; i < LI / 4; i += 256)
    inv_l[i] = SMOOTHF / (rs_t[b * LI + i0 + i] + EPSF);
  __syncthreads();
  const float* g = G + (size_t)b * LI * LT + (size_t)i0 * LT + t;
  float m = -1e30f, s = 0.f;
  for (int i = 0; i < LI / 4; ++i) {
    float x  = fmaxf(g[(size_t)i * LT], 0.f) * inv_l[i];
    float mn = fmaxf(m, x);
    s = s * __expf(m - mn) + __expf(x - mn);
    m = mn;
  }
  pm[(b * 4 + iq) * LT + t] = m;
  ps[(b * 4 + iq) * LT + t] = s;
}

__global__ __launch_bounds__(256) void attn_img_combine_kernel(
    const float* __restrict__ pm, const float* __restrict__ ps,
    float* __restrict__ m_out, float* __restrict__ s_out) {
  int b = blockIdx.x, t = threadIdx.x;
  float m = -1e30f;
  #pragma unroll
  for (int q = 0; q < 4; ++q) m = fmaxf(m, pm[(b * 4 + q) * LT + t]);
  float s = 0.f;
  #pragma unroll
  for (int q = 0; q < 4; ++q) s += ps[(b * 4 + q) * LT + t] * __expf(pm[(b * 4 + q) * LT + t] - m);
  m_out[b * LT + t] = m;
  s_out[b * LT + t] = s;
}

// ---------------- attn_img writer (G[i,t] -> attn[t,i] via LDS transpose) ----------------
__global__ __launch_bounds__(256) void attn_img_write_kernel(
    const float* __restrict__ G, const float* __restrict__ rs_t,
    const float* __restrict__ m_in, const float* __restrict__ s_in,
    float* __restrict__ out_f32, ushort* __restrict__ out_bf16) {
  __shared__ float T[64][65];
  int b  = blockIdx.y;
  int ti = blockIdx.x % (LI / 64);
  int tt = blockIdx.x / (LI / 64);
  int i0 = ti * 64, t0 = tt * 64;
  int tid = threadIdx.x;
  #pragma unroll
  for (int j = 0; j < 4; ++j) {
    int q = tid + j * 256;
    int row = q >> 4;
    int c4  = (q & 15) << 2;
    float4 gv = *reinterpret_cast<const float4*>(G + (size_t)b * LI * LT + (size_t)(i0 + row) * LT + t0 + c4);
    float inv = SMOOTHF / (rs_t[b * LI + i0 + row] + EPSF);
    float4 mt = *reinterpret_cast<const float4*>(m_in + b * LT + t0 + c4);
    float4 st = *reinterpret_cast<const float4*>(s_in + b * LT + t0 + c4);
    T[c4 + 0][row] = __expf(fmaxf(gv.x, 0.f) * inv - mt.x) / st.x;
    T[c4 + 1][row] = __expf(fmaxf(gv.y, 0.f) * inv - mt.y) / st.y;
    T[c4 + 2][row] = __expf(fmaxf(gv.z, 0.f) * inv - mt.z) / st.z;
    T[c4 + 3][row] = __expf(fmaxf(gv.w, 0.f) * inv - mt.w) / st.w;
  }
  __syncthreads();
  #pragma unroll
  for (int j = 0; j < 4; ++j) {
    int q = tid + j * 256;
    int row = q >> 4;
    int c4  = (q & 15) << 2;
    float4 o = make_float4(T[row][c4], T[row][c4 + 1], T[row][c4 + 2], T[row][c4 + 3]);
    size_t off = (size_t)b * LT * LI + (size_t)(t0 + row) * LI + i0 + c4;
    *reinterpret_cast<float4*>(out_f32 + off) = o;
    ushort4 ob = make_ushort4(f2b(o.x), f2b(o.y), f2b(o.z), f2b(o.w));
    *reinterpret_cast<ushort4*>(out_bf16 + off) = ob;
  }
}

// ---------------- launch ----------------
extern "C" void kernel_launch(void* const* d_in, const int* in_sizes, int n_in,
                              void* d_out, int out_size, void* d_ws, size_t ws_size,
                              hipStream_t stream) {
  const float* txt   = (const float*)d_in[0];
  const float* img   = (const float*)d_in[1];
  const float* W_txt = (const float*)d_in[2];
  const float* b_txt = (const float*)d_in[3];
  const float* W_img = (const float*)d_in[4];
  const float* b_img = (const float*)d_in[5];

  float* out          = (float*)d_out;
  float* out_txt      = out;
  float* out_img      = out + (size_t)B_ * LT * HD;
  float* out_attn_img = out_img + (size_t)B_ * LI * HD;
  float* out_attn_txt = out_attn_img + (size_t)B_ * LT * LI;

  char* w = (char*)d_ws;
  auto alloc = [&](size_t bytes) -> char* {
    char* p = w; w += (bytes + 255) & ~(size_t)255; return p;
  };
  ushort* txt_b  = (ushort*)alloc((size_t)B_ * LT * HD * 2);
  ushort* img_b  = (ushort*)alloc((size_t)B_ * LI * HD * 2);
  ushort* Wt_b   = (ushort*)alloc((size_t)HD * HD * 2);
  ushort* Wi_b   = (ushort*)alloc((size_t)HD * HD * 2);
  float*  Gm     = (float*) alloc((size_t)B_ * LI * LT * 4);
  float*  rs_t   = (float*) alloc((size_t)B_ * LI * 4);
  float*  rs_i   = (float*) alloc((size_t)B_ * LT * 4);
  float*  pm     = (float*) alloc((size_t)B_ * 4 * LT * 4);
  float*  ps     = (float*) alloc((size_t)B_ * 4 * LT * 4);
  float*  mi     = (float*) alloc((size_t)B_ * LT * 4);
  float*  si     = (float*) alloc((size_t)B_ * LT * 4);
  ushort* ai_b   = (ushort*)alloc((size_t)B_ * LT * LI * 2);
  ushort* at_b   = (ushort*)alloc((size_t)B_ * LI * LT * 2);
  ushort* txtAE  = (ushort*)alloc((size_t)B_ * LT * HD * 2);
  ushort* imgAE  = (ushort*)alloc((size_t)B_ * LI * HD * 2);
  (void)ws_size; (void)in_sizes; (void)n_in; (void)out_size;  // ~571 MB (proven fits r2)

  // bf16 conversions
  cvt_bf16_kernel<<<2048, 256, 0, stream>>>(txt, txt_b, B_ * LT * HD / 4);
  cvt_bf16_kernel<<<2048, 256, 0, stream>>>(img, img_b, B_ * LI * HD / 4);
  cvt_bf16_kernel<<<1024, 256, 0, stream>>>(W_txt, Wt_b, HD * HD / 4);
  cvt_bf16_kernel<<<1024, 256, 0, stream>>>(W_img, Wi_b, HD * HD / 4);

  // G[b,i,t] = img[b,i,:].txt[b,t,:]   (NT, M=576 pred, N=256)
  dim3 gG(5 * (LT / 128), B_);
  gemm128<false, true, false, false, false><<<gG, 256, 0, stream>>>(
      img_b, txt_b, nullptr, Gm, LI, LT, HD,
      (long)LI * HD, (long)LT * HD, (long)LI * LT, HD, HD, LT);

  rowsum_relu_kernel<<<B_ * LI / 4, 256, 0, stream>>>(Gm, rs_t);
  colsum_relu_kernel<<<B_, 256, 0, stream>>>(Gm, rs_i);

  attn_txt_kernel<<<B_ * LI / 4, 256, 0, stream>>>(Gm, rs_i, out_attn_txt, at_b);

  attn_img_stats_kernel<<<dim3(B_, 4), 256, 0, stream>>>(Gm, rs_t, pm, ps);
  attn_img_combine_kernel<<<B_, 256, 0, stream>>>(pm, ps, mi, si);
  attn_img_write_kernel<<<dim3((LT / 64) * (LI / 64), B_), 256, 0, stream>>>(
      Gm, rs_t, mi, si, out_attn_img, ai_b);

  // txtAE = attn_img . img   (BT: B=[K=LI][N=HD])
  dim3 g1((LT / 128) * (HD / 128), B_);
  gemm128<true, false, true, false, false><<<g1, 256, 0, stream>>>(
      ai_b, img_b, nullptr, txtAE, LT, HD, LI,
      (long)LT * LI, (long)LI * HD, (long)LT * HD, LI, HD, HD);

  // imgAE = attn_txt . txt   (BT, M=576 pred)
  dim3 g2(5 * (HD / 128), B_);
  gemm128<true, true, true, false, false><<<g2, 256, 0, stream>>>(
      at_b, txt_b, nullptr, imgAE, LI, HD, LT,
      (long)LI * LT, (long)LT * HD, (long)LI * HD, LT, HD, HD);

  // FC heads flattened over batch (shared W): relu(x @ W^T + b), NT, XCD swizzle
  dim3 gf1((B_ * LT / 128) * (HD / 128), 1);   // 2048 blocks
  gemm128<false, false, false, true, true><<<gf1, 256, 0, stream>>>(
      txtAE, Wt_b, b_txt, out_txt, B_ * LT, HD, HD,
      0L, 0L, 0L, HD, HD, HD);
  dim3 gf2((B_ * LI / 128) * (HD / 128), 1);   // 4608 blocks
  gemm128<false, false, false, true, true><<<gf2, 256, 0, stream>>>(
      imgAE, Wi_b, b_img, out_img, B_ * LI, HD, HD,
      0L, 0L, 0L, HD, HD, HD);
}